// Round 2
// baseline (179.666 us; speedup 1.0000x reference)
//
#include <hip/hip_runtime.h>
#include <stdint.h>

typedef unsigned short ushort_t;
typedef __attribute__((ext_vector_type(8))) short short8;
typedef __attribute__((ext_vector_type(4))) float f32x4;
typedef __attribute__((ext_vector_type(4))) unsigned int u32x4;

#define TOK  16384
#define DIM  512
#define NPAIR 64          // pmin*8+pmax, only pmin<pmax used (28 live bins)
#define MAXROWTILES 156   // sum ceil(cnt/128) <= 128 + 28

// ---- helpers ----
__device__ __forceinline__ unsigned short f2bf(float f) {  // RNE f32->bf16
  union { float f; uint32_t u; } v; v.f = f;
  uint32_t u = v.u;
  uint32_t r = (u + 0x7fffu + ((u >> 16) & 1u)) >> 16;
  return (unsigned short)r;
}

// ---- kernel 1: router -> per-token weights w4[t][4]={w_pmin,w_pmax,p0,p1},
//      pair id, and per-pair counts ----
__global__ void k_router(const float* __restrict__ sl, const float* __restrict__ shl,
                         float* __restrict__ w4, int* __restrict__ pairid,
                         int* __restrict__ cnt) {
  int n = blockIdx.x * 256 + threadIdx.x;
  if (n >= TOK) return;
  float l[8];
  float m = -1e30f;
#pragma unroll
  for (int i = 0; i < 8; ++i) { l[i] = sl[n*8 + i]; m = fmaxf(m, l[i]); }
  float s = 0.f;
#pragma unroll
  for (int i = 0; i < 8; ++i) { l[i] = expf(l[i] - m); s += l[i]; }
  float inv = 1.f / s;
#pragma unroll
  for (int i = 0; i < 8; ++i) l[i] *= inv;
  // top-2, ties -> lowest index (matches lax.top_k)
  int i1 = 0; float v1 = l[0];
#pragma unroll
  for (int i = 1; i < 8; ++i) if (l[i] > v1) { v1 = l[i]; i1 = i; }
  int i2 = -1; float v2 = -1.f;
#pragma unroll
  for (int i = 0; i < 8; ++i) if (i != i1 && l[i] > v2) { v2 = l[i]; i2 = i; }
  float rs = 1.f / (v1 + v2 + 1e-6f);
  float w1 = v1 * rs, w2 = v2 * rs;
  int pmin, pmax; float wa, wb;
  if (i1 < i2) { pmin = i1; pmax = i2; wa = w1; wb = w2; }
  else         { pmin = i2; pmax = i1; wa = w2; wb = w1; }
  float s0 = shl[n*2], s1 = shl[n*2 + 1];
  float mm = fmaxf(s0, s1);
  float e0 = expf(s0 - mm), e1 = expf(s1 - mm);
  float si = 1.f / (e0 + e1);
  w4[n*4 + 0] = wa;
  w4[n*4 + 1] = wb;
  w4[n*4 + 2] = e0 * si;
  w4[n*4 + 3] = e1 * si;
  int p = pmin * 8 + pmax;
  pairid[n] = p;
  atomicAdd(&cnt[p], 1);
}

// ---- kernel 2: serial scan over 64 bins (trivial work) ----
__global__ void k_scan(const int* __restrict__ cnt, int* __restrict__ off,
                       int* __restrict__ cursor, int* __restrict__ ts,
                       ushort_t* __restrict__ idx) {
  if (blockIdx.x == 0 && threadIdx.x == 0) {
    int a = 0, t = 0;
    for (int p = 0; p < NPAIR; ++p) {
      off[p] = a; cursor[p] = a; ts[p] = t;
      a += cnt[p];
      t += (cnt[p] + 127) >> 7;
    }
    ts[NPAIR] = t;
    for (int i = 0; i < 128; ++i) idx[TOK + i] = 0;  // pad tail (poisoned ws)
  }
}

// ---- kernel 3: fill packed token index buffer ----
__global__ void k_fill(const int* __restrict__ pairid, int* __restrict__ cursor,
                       ushort_t* __restrict__ idx) {
  int n = blockIdx.x * 256 + threadIdx.x;
  if (n >= TOK) return;
  int p = pairid[n];
  int s = atomicAdd(&cursor[p], 1);
  idx[s] = (ushort_t)n;
}

// ---- kernel 4: x fp32 -> bf16 ----
__global__ void k_cvtx(const float* __restrict__ x, ushort_t* __restrict__ xb) {
  int i = (blockIdx.x * 256 + threadIdx.x) * 8;
  f32x4 v0 = *(const f32x4*)(x + i);
  f32x4 v1 = *(const f32x4*)(x + i + 4);
  u32x4 o;
  o[0] = (uint32_t)f2bf(v0[0]) | ((uint32_t)f2bf(v0[1]) << 16);
  o[1] = (uint32_t)f2bf(v0[2]) | ((uint32_t)f2bf(v0[3]) << 16);
  o[2] = (uint32_t)f2bf(v1[0]) | ((uint32_t)f2bf(v1[1]) << 16);
  o[3] = (uint32_t)f2bf(v1[2]) | ((uint32_t)f2bf(v1[3]) << 16);
  *(u32x4*)(xb + i) = o;
}

// ---- kernel 5: W[e][d][f] fp32 -> Wt[e][f][d] bf16 ----
__global__ void k_trw(const float* __restrict__ wspec, const float* __restrict__ wsh,
                      ushort_t* __restrict__ wt) {
  __shared__ float t[32][33];
  int e = blockIdx.z;
  const float* src = (e < 8) ? (wspec + e * DIM * DIM) : (wsh + (e - 8) * DIM * DIM);
  int tx = threadIdx.x, ty = threadIdx.y;
  int d = blockIdx.y * 32 + ty, f = blockIdx.x * 32 + tx;
  t[ty][tx] = src[d * DIM + f];
  __syncthreads();
  int fo = blockIdx.x * 32 + ty, dd = blockIdx.y * 32 + tx;
  wt[(size_t)e * DIM * DIM + fo * DIM + dd] = f2bf(t[tx][ty]);
}

// ---- kernel 6: pair-grouped sparse MoE GEMM ----
// Block = (pair row-tile of 128 gathered tokens) x (128-col tile).
// 4 sequential expert passes {pmin, pmax, 8, 9}, each a pure bf16 MFMA
// K-loop (no per-kstep VALU); per-pass epilogue fold acc_out += w_j * acc.
__global__ __launch_bounds__(256, 2)
void k_moe(const ushort_t* __restrict__ xb, const ushort_t* __restrict__ wt,
           const float* __restrict__ w4, const ushort_t* __restrict__ idx,
           const int* __restrict__ off, const int* __restrict__ cnt,
           const int* __restrict__ ts, const float* __restrict__ bspec,
           const float* __restrict__ bsh, float* __restrict__ out) {
  __shared__ ushort_t aB[2][128 * 64];   // 2 x 16 KB gathered-x tile
  __shared__ ushort_t bB[2][128 * 64];   // 2 x 16 KB W tile
  __shared__ float wLT[4 * 128];         // per-pass per-row weight
  __shared__ float bL[4 * 128];          // per-pass bias slice
  __shared__ int   iL[128];              // token ids of this row-tile

  const int tid  = threadIdx.x;
  const int lane = tid & 63;
  const int w    = tid >> 6;
  const int wr   = w >> 1, wc = w & 1;

  // XCD-aware swizzle: 624 = 8 x 78; keep a row-tile's 4 col-blocks on one XCD
  int bx   = blockIdx.x;
  int slot = (bx & 7) * 78 + (bx >> 3);
  int r    = slot >> 2, cdx = slot & 3;
  if (r >= ts[NPAIR]) return;
  int p = 0;
#pragma unroll 1
  for (int q = 0; q < NPAIR; ++q) { if (r >= ts[q] && r < ts[q + 1]) { p = q; break; } }
  const int tstart = r - ts[p];
  const int base   = off[p] + (tstart << 7);
  int cl = cnt[p] - (tstart << 7); if (cl > 128) cl = 128;
  const int e0 = p >> 3, e1 = p & 7;
  const int tcol = cdx << 7;

  // stage row-tile metadata
  for (int i = tid; i < 128; i += 256) iL[i] = (int)idx[base + i];
  for (int i = tid; i < 512; i += 256) {
    int j = i >> 7, rs = i & 127;
    wLT[i] = (rs < cl) ? w4[(int)idx[base + rs] * 4 + j] : 0.f;
  }
  for (int i = tid; i < 512; i += 256) {
    int j = i >> 7, col = i & 127;
    int e = (j == 0) ? e0 : (j == 1) ? e1 : (j == 2) ? 8 : 9;
    bL[i] = (e < 8) ? bspec[e * DIM + tcol + col] : bsh[(e - 8) * DIM + tcol + col];
  }

  // per-lane staging offsets; global source pre-swizzled (byte ^= (row&7)<<4)
  // so linear global_load_lds dest + swizzled ds_read agree.
  int aoff[4], boff[4];
  const int pb = (w << 12) + (lane << 4);
#pragma unroll
  for (int i = 0; i < 4; ++i) {
    int pp  = pb + (i << 10);
    int row = pp >> 7;
    int kb  = (pp & 127) ^ ((row & 7) << 4);
    int tok = (int)idx[base + row];
    aoff[i] = tok * DIM + (kb >> 1);
    boff[i] = (tcol + row) * DIM + (kb >> 1);
  }

  auto stageA = [&](int ks, int buf) {
#pragma unroll
    for (int i = 0; i < 4; ++i)
      __builtin_amdgcn_global_load_lds(
          (const __attribute__((address_space(1))) void*)(xb + aoff[i] + (ks << 6)),
          (__attribute__((address_space(3))) void*)((char*)(&aB[buf][0]) + (w << 12) + (i << 10)),
          16, 0, 0);
  };
  auto stageB = [&](int e, int ks, int buf) {
    const ushort_t* s = wt + ((size_t)e << 18) + (ks << 6);
#pragma unroll
    for (int i = 0; i < 4; ++i)
      __builtin_amdgcn_global_load_lds(
          (const __attribute__((address_space(1))) void*)(s + boff[i]),
          (__attribute__((address_space(3))) void*)((char*)(&bB[buf][0]) + (w << 12) + (i << 10)),
          16, 0, 0);
  };

  f32x4 accO[4][4];
#pragma unroll
  for (int a = 0; a < 4; ++a)
#pragma unroll
    for (int b = 0; b < 4; ++b) accO[a][b] = (f32x4){0.f, 0.f, 0.f, 0.f};

  stageA(0, 0);
  stageB(e0, 0, 0);

#pragma unroll 1
  for (int j = 0; j < 4; ++j) {
    f32x4 acc[4][4];
#pragma unroll
    for (int a = 0; a < 4; ++a)
#pragma unroll
      for (int b = 0; b < 4; ++b) acc[a][b] = (f32x4){0.f, 0.f, 0.f, 0.f};

#pragma unroll 1
    for (int ks = 0; ks < 8; ++ks) {
      int s = (j << 3) | ks;
      __syncthreads();  // staged tile (buf = s&1) complete & visible
      if (s < 31) {
        int ns = s + 1, nks = ns & 7, nj = ns >> 3, nbuf = ns & 1;
        int ne = (nj == 0) ? e0 : (nj == 1) ? e1 : (nj == 2) ? 8 : 9;
        stageA(nks, nbuf);
        stageB(ne, nks, nbuf);
      }
      const int buf = s & 1;
      const char* ab = (const char*)(&aB[buf][0]);
      const char* bb = (const char*)(&bB[buf][0]);
      u32x4 af[4][2], bf[4][2];
#pragma unroll
      for (int rb = 0; rb < 4; ++rb) {
        int row = wr * 64 + rb * 16 + (lane & 15);
#pragma unroll
        for (int ksl = 0; ksl < 2; ++ksl) {
          int kb = ((ksl << 6) + ((lane >> 4) << 4)) ^ ((row & 7) << 4);
          af[rb][ksl] = *(const u32x4*)(ab + row * 128 + kb);
        }
      }
#pragma unroll
      for (int cb = 0; cb < 4; ++cb) {
        int col = wc * 64 + cb * 16 + (lane & 15);
#pragma unroll
        for (int ksl = 0; ksl < 2; ++ksl) {
          int kb = ((ksl << 6) + ((lane >> 4) << 4)) ^ ((col & 7) << 4);
          bf[cb][ksl] = *(const u32x4*)(bb + col * 128 + kb);
        }
      }
#pragma unroll
      for (int ksl = 0; ksl < 2; ++ksl)
#pragma unroll
        for (int rb = 0; rb < 4; ++rb) {
          short8 a8 = __builtin_bit_cast(short8, af[rb][ksl]);
#pragma unroll
          for (int cb = 0; cb < 4; ++cb) {
            short8 b8 = __builtin_bit_cast(short8, bf[cb][ksl]);
            acc[rb][cb] = __builtin_amdgcn_mfma_f32_16x16x32_bf16(a8, b8, acc[rb][cb], 0, 0, 0);
          }
        }
    }
    // fold pass j: acc_out += w_j[row] * acc   (register-only + 4 ds_read_b128)
#pragma unroll
    for (int rb = 0; rb < 4; ++rb) {
      int rloc = wr * 64 + rb * 16 + ((lane >> 4) << 2);
      f32x4 wv = *(const f32x4*)&wLT[(j << 7) + rloc];
#pragma unroll
      for (int cb = 0; cb < 4; ++cb) accO[rb][cb] += wv * acc[rb][cb];
    }
  }

  // epilogue: bias Σ_j w_j*b_ej[col], scatter rows by token id, predicated
#pragma unroll
  for (int rb = 0; rb < 4; ++rb) {
    int rloc = wr * 64 + rb * 16 + ((lane >> 4) << 2);
    f32x4 wv[4];
#pragma unroll
    for (int j = 0; j < 4; ++j) wv[j] = *(const f32x4*)&wLT[(j << 7) + rloc];
    int tok[4]; bool pr[4];
#pragma unroll
    for (int q = 0; q < 4; ++q) { int rs = rloc + q; pr[q] = rs < cl; tok[q] = iL[rs]; }
#pragma unroll
    for (int cb = 0; cb < 4; ++cb) {
      int cloc = wc * 64 + cb * 16 + (lane & 15);
      f32x4 v = accO[rb][cb];
#pragma unroll
      for (int j = 0; j < 4; ++j) {
        float bj = bL[(j << 7) + cloc];
        v += wv[j] * bj;
      }
#pragma unroll
      for (int q = 0; q < 4; ++q)
        if (pr[q]) out[(size_t)tok[q] * DIM + tcol + cloc] = v[q];
    }
  }
}

extern "C" void kernel_launch(void* const* d_in, const int* in_sizes, int n_in,
                              void* d_out, int out_size, void* d_ws, size_t ws_size,
                              hipStream_t stream) {
  (void)in_sizes; (void)n_in; (void)out_size; (void)ws_size;
  const float* x   = (const float*)d_in[0];
  const float* srl = (const float*)d_in[1];
  const float* shl = (const float*)d_in[2];
  const float* sW  = (const float*)d_in[3];
  const float* sb  = (const float*)d_in[4];
  const float* hW  = (const float*)d_in[5];
  const float* hb  = (const float*)d_in[6];
  float* out = (float*)d_out;

  // workspace layout (~21.4 MB)
  char* ws = (char*)d_ws;
  float*    w4     = (float*)ws;                           ws += TOK * 4 * 4;       // 256 KB
  int*      pairid = (int*)ws;                             ws += TOK * 4;           // 64 KB
  ushort_t* idx    = (ushort_t*)ws;                        ws += (TOK + 128) * 2 + 256;
  int*      cntp   = (int*)ws;                             ws += NPAIR * 4;
  int*      offp   = (int*)ws;                             ws += NPAIR * 4;
  int*      curp   = (int*)ws;                             ws += NPAIR * 4;
  int*      tsp    = (int*)ws;                             ws += (NPAIR + 1) * 4 + 252;
  ushort_t* xb     = (ushort_t*)ws;                        ws += (size_t)TOK * DIM * 2;  // 16 MB
  ushort_t* wt     = (ushort_t*)ws;                                                  // 5.25 MB

  hipMemsetAsync(cntp, 0, NPAIR * sizeof(int), stream);
  k_router<<<TOK / 256, 256, 0, stream>>>(srl, shl, w4, pairid, cntp);
  k_scan<<<1, 64, 0, stream>>>(cntp, offp, curp, tsp, idx);
  k_fill<<<TOK / 256, 256, 0, stream>>>(pairid, curp, idx);
  k_cvtx<<<(TOK * DIM) / (8 * 256), 256, 0, stream>>>(x, xb);
  dim3 tb(32, 32, 1), tg(16, 16, 10);
  k_trw<<<tg, tb, 0, stream>>>(sW, hW, wt);
  k_moe<<<MAXROWTILES * 4, 256, 0, stream>>>(xb, wt, w4, idx, offp, cntp, tsp, sb, hb, out);
}

// Round 3
// 151.950 us; speedup vs baseline: 1.1824x; 1.1824x over previous
//
#include <hip/hip_runtime.h>
#include <stdint.h>

typedef unsigned short ushort_t;
typedef __attribute__((ext_vector_type(8))) short short8;
typedef __attribute__((ext_vector_type(4))) float f32x4;
typedef __attribute__((ext_vector_type(4))) unsigned int u32x4;

#define TOK  16384
#define DIM  512
#define NPAIR 64          // pmin*8+pmax, only pmin<pmax used (28 live bins)
#define MAXTILES 156      // sum ceil(cnt/128) <= 128 + 28

// ---- helpers ----
__device__ __forceinline__ unsigned short f2bf(float f) {  // RNE f32->bf16
  union { float f; uint32_t u; } v; v.f = f;
  uint32_t u = v.u;
  uint32_t r = (u + 0x7fffu + ((u >> 16) & 1u)) >> 16;
  return (unsigned short)r;
}

// ---- kernel 1: router -> w4[t][4], pairid, per-pair counts (block-aggregated) ----
__global__ void k_router(const float* __restrict__ sl, const float* __restrict__ shl,
                         float* __restrict__ w4, int* __restrict__ pairid,
                         int* __restrict__ cnt) {
  __shared__ int h[NPAIR];
  int tid = threadIdx.x;
  int n = blockIdx.x * 256 + tid;
  if (tid < NPAIR) h[tid] = 0;
  __syncthreads();
  float l[8];
  float m = -1e30f;
#pragma unroll
  for (int i = 0; i < 8; ++i) { l[i] = sl[n*8 + i]; m = fmaxf(m, l[i]); }
  float s = 0.f;
#pragma unroll
  for (int i = 0; i < 8; ++i) { l[i] = expf(l[i] - m); s += l[i]; }
  float inv = 1.f / s;
#pragma unroll
  for (int i = 0; i < 8; ++i) l[i] *= inv;
  int i1 = 0; float v1 = l[0];
#pragma unroll
  for (int i = 1; i < 8; ++i) if (l[i] > v1) { v1 = l[i]; i1 = i; }
  int i2 = -1; float v2 = -1.f;
#pragma unroll
  for (int i = 0; i < 8; ++i) if (i != i1 && l[i] > v2) { v2 = l[i]; i2 = i; }
  float rs = 1.f / (v1 + v2 + 1e-6f);
  float w1 = v1 * rs, w2 = v2 * rs;
  int pmin, pmax; float wa, wb;
  if (i1 < i2) { pmin = i1; pmax = i2; wa = w1; wb = w2; }
  else         { pmin = i2; pmax = i1; wa = w2; wb = w1; }
  float s0 = shl[n*2], s1 = shl[n*2 + 1];
  float mm = fmaxf(s0, s1);
  float e0 = expf(s0 - mm), e1 = expf(s1 - mm);
  float si = 1.f / (e0 + e1);
  w4[n*4 + 0] = wa;
  w4[n*4 + 1] = wb;
  w4[n*4 + 2] = e0 * si;
  w4[n*4 + 3] = e1 * si;
  int p = pmin * 8 + pmax;
  pairid[n] = p;
  atomicAdd(&h[p], 1);                 // LDS atomic, low contention
  __syncthreads();
  if (tid < NPAIR && h[tid]) atomicAdd(&cnt[tid], h[tid]);  // <=64 per address
}

// ---- kernel 2: single-wave scan over 64 bins -> off/cursor/tileinfo ----
__global__ void k_scan(const int* __restrict__ cnt, int* __restrict__ off,
                       int* __restrict__ cursor, int* __restrict__ tsinfo,
                       int* __restrict__ tileinfo, ushort_t* __restrict__ idx) {
  int l = threadIdx.x;  // 64 threads = 1 wave
  int c = cnt[l];
  int t = (c + 127) >> 7;
  int sc = c, st = t;
#pragma unroll
  for (int d = 1; d < 64; d <<= 1) {
    int vc = __shfl_up(sc, d, 64);
    int vt = __shfl_up(st, d, 64);
    if (l >= d) { sc += vc; st += vt; }
  }
  int offv = sc - c, tsv = st - t;
  off[l] = offv; cursor[l] = offv;
  if (l == 63) tsinfo[64] = st;               // total row-tiles
  for (int q = 0; q < t; ++q) tileinfo[tsv + q] = (l << 16) | q;  // (pair, tstart)
  for (int i = l; i < 128; i += 64) idx[TOK + i] = 0;  // pad tail
}

// ---- kernel 3: fill packed token index (block-aggregated reservation) ----
__global__ void k_fill(const int* __restrict__ pairid, int* __restrict__ cursor,
                       ushort_t* __restrict__ idx) {
  __shared__ int hcnt[NPAIR];
  __shared__ int hbase[NPAIR];
  int tid = threadIdx.x;
  int n = blockIdx.x * 256 + tid;
  if (tid < NPAIR) hcnt[tid] = 0;
  __syncthreads();
  int p = pairid[n];
  int r = atomicAdd(&hcnt[p], 1);      // LDS atomic
  __syncthreads();
  if (tid < NPAIR && hcnt[tid]) hbase[tid] = atomicAdd(&cursor[tid], hcnt[tid]);
  __syncthreads();
  idx[hbase[p] + r] = (ushort_t)n;
}

// ---- kernel 4: fused gather + fp32->bf16 pack: xg[slot] = bf16(x[idx[slot]]) ----
__global__ void k_gather(const float* __restrict__ x, const ushort_t* __restrict__ idx,
                         ushort_t* __restrict__ xg) {
  int row = blockIdx.x * 4 + (threadIdx.x >> 6);
  int lane = threadIdx.x & 63;
  int t = (int)idx[row];
  const float* src = x + (size_t)t * DIM + lane * 8;
  f32x4 v0 = *(const f32x4*)src;
  f32x4 v1 = *(const f32x4*)(src + 4);
  u32x4 o;
  o[0] = (uint32_t)f2bf(v0[0]) | ((uint32_t)f2bf(v0[1]) << 16);
  o[1] = (uint32_t)f2bf(v0[2]) | ((uint32_t)f2bf(v0[3]) << 16);
  o[2] = (uint32_t)f2bf(v1[0]) | ((uint32_t)f2bf(v1[1]) << 16);
  o[3] = (uint32_t)f2bf(v1[2]) | ((uint32_t)f2bf(v1[3]) << 16);
  *(u32x4*)(xg + (size_t)row * DIM + lane * 8) = o;
}

// ---- kernel 5: W[e][d][f] fp32 -> Wt[e][f][d] bf16 ----
__global__ void k_trw(const float* __restrict__ wspec, const float* __restrict__ wsh,
                      ushort_t* __restrict__ wt) {
  __shared__ float t[32][33];
  int e = blockIdx.z;
  const float* src = (e < 8) ? (wspec + e * DIM * DIM) : (wsh + (e - 8) * DIM * DIM);
  int tx = threadIdx.x, ty = threadIdx.y;
  int d = blockIdx.y * 32 + ty, f = blockIdx.x * 32 + tx;
  t[ty][tx] = src[d * DIM + f];
  __syncthreads();
  int fo = blockIdx.x * 32 + ty, dd = blockIdx.y * 32 + tx;
  wt[(size_t)e * DIM * DIM + fo * DIM + dd] = f2bf(t[tx][ty]);
}

// ---- kernel 6: pair-grouped sparse MoE GEMM, counted-vmcnt 4-buffer pipeline ----
// Block = 128 packed rows x 128 cols. 4 expert passes {e0,e1,8,9} x 16 K-steps
// (BK=32). Stage 3 steps ahead; vmcnt(8)+s_barrier per step (never drain in loop).
// LDS tile layout: [64 ldsrows x 128B]; tile-row t -> (ldsrow=t>>1, half=t&1);
// 16B-slot swizzle: phys = orig ^ ((ldsrow&7)<<4)  (bijective involution).
__global__ __launch_bounds__(256, 2)
void k_moe(const ushort_t* __restrict__ xg, const ushort_t* __restrict__ wt,
           const float* __restrict__ w4, const ushort_t* __restrict__ idx,
           const int* __restrict__ off, const int* __restrict__ cnt,
           const int* __restrict__ tsinfo, const int* __restrict__ tileinfo,
           const float* __restrict__ bspec, const float* __restrict__ bsh,
           float* __restrict__ out) {
  __shared__ char ldsA[4 * 8192];
  __shared__ char ldsB[4 * 8192];
  __shared__ float wLT[4 * 128];
  __shared__ float bL[4 * 128];

  const int tid  = threadIdx.x;
  const int lane = tid & 63;
  const int w    = tid >> 6;
  const int wr   = w >> 1, wc = w & 1;

  // XCD swizzle: 624 = 8 x 78; a row-tile's 4 col-blocks stay on one XCD
  int bx   = blockIdx.x;
  int slot = (bx & 7) * 78 + (bx >> 3);
  int r    = slot >> 2, cdx = slot & 3;
  if (r >= tsinfo[64]) return;
  int info = tileinfo[r];
  int p = info >> 16, tstart = info & 0xffff;
  const int base = off[p] + (tstart << 7);
  int cl = cnt[p] - (tstart << 7); if (cl > 128) cl = 128;
  const int e0 = p >> 3, e1 = p & 7;
  const int tcol = cdx << 7;

  // staging source offsets (elements): invert the LDS swizzle at the source
  int aoff[2];
#pragma unroll
  for (int q = 0; q < 2; ++q) {
    int pp   = (q << 12) + tid * 16;       // LDS byte within 8KB buffer
    int lr   = pp >> 7;
    int orig = (pp & 127) ^ ((lr & 7) << 4);
    int t    = lr * 2 + (orig >> 6);
    int kb   = orig & 63;
    aoff[q]  = t * DIM + (kb >> 1);
  }
  const ushort_t* aSrc = xg + (size_t)base * DIM;
  const ushort_t* bSrc = wt + (size_t)tcol * DIM;

  // swizzled read offsets (bytes within 8KB buffer)
  int aRd[4], bRd[4];
#pragma unroll
  for (int i = 0; i < 4; ++i) {
    int t  = wr * 64 + i * 16 + (lane & 15);
    int lr = t >> 1;
    int sl = ((t & 1) << 6) | ((lane >> 4) << 4);
    aRd[i] = lr * 128 + (sl ^ ((lr & 7) << 4));
    int c  = wc * 64 + i * 16 + (lane & 15);
    int lc = c >> 1;
    int sc = ((c & 1) << 6) | ((lane >> 4) << 4);
    bRd[i] = lc * 128 + (sc ^ ((lc & 7) << 4));
  }

  auto stage = [&](int s) {   // 4 vmem instr per wave per call
    int ks = s & 15, buf = s & 3, j = s >> 4;
    int e = (j == 0) ? e0 : (j == 1) ? e1 : (j == 2) ? 8 : 9;
    const ushort_t* a = aSrc + (ks << 5);
    const ushort_t* b = bSrc + ((size_t)e << 18) + (ks << 5);
#pragma unroll
    for (int q = 0; q < 2; ++q) {
      __builtin_amdgcn_global_load_lds(
          (const __attribute__((address_space(1))) void*)(a + aoff[q]),
          (__attribute__((address_space(3))) void*)(ldsA + (buf << 13) + (q << 12) + tid * 16),
          16, 0, 0);
      __builtin_amdgcn_global_load_lds(
          (const __attribute__((address_space(1))) void*)(b + aoff[q]),
          (__attribute__((address_space(3))) void*)(ldsB + (buf << 13) + (q << 12) + tid * 16),
          16, 0, 0);
    }
  };

  stage(0); stage(1); stage(2);

  for (int i = tid; i < 512; i += 256) {
    int j = i >> 7, rs = i & 127;
    wLT[i] = (rs < cl) ? w4[(int)idx[base + rs] * 4 + j] : 0.f;
  }
  for (int i = tid; i < 512; i += 256) {
    int j = i >> 7, col = i & 127;
    int e = (j == 0) ? e0 : (j == 1) ? e1 : (j == 2) ? 8 : 9;
    bL[i] = (e < 8) ? bspec[e * DIM + tcol + col] : bsh[(e - 8) * DIM + tcol + col];
  }
  __syncthreads();   // drains prologue stages 0-2; publishes wLT/bL

  f32x4 acc[4][4], accO[4][4];
#pragma unroll
  for (int a = 0; a < 4; ++a)
#pragma unroll
    for (int b = 0; b < 4; ++b) { acc[a][b] = (f32x4){0,0,0,0}; accO[a][b] = (f32x4){0,0,0,0}; }

#pragma unroll 1
  for (int s = 0; s < 64; ++s) {
    if (s >= 3) {
      // steady: stages s+1,s+2 in flight (8 instr) -> vmcnt(8) proves stage(s) landed
      if (s < 62)       asm volatile("s_waitcnt vmcnt(8)" ::: "memory");
      else if (s == 62) asm volatile("s_waitcnt vmcnt(4)" ::: "memory");
      else              asm volatile("s_waitcnt vmcnt(0)" ::: "memory");
    }
    __builtin_amdgcn_s_barrier();
    __builtin_amdgcn_sched_barrier(0);   // pin: nothing moves across the barrier
    if (s <= 60) stage(s + 3);

    const char* ab = ldsA + ((s & 3) << 13);
    const char* bb = ldsB + ((s & 3) << 13);
    u32x4 af[4], bf[4];
#pragma unroll
    for (int i = 0; i < 4; ++i) af[i] = *(const u32x4*)(ab + aRd[i]);
#pragma unroll
    for (int i = 0; i < 4; ++i) bf[i] = *(const u32x4*)(bb + bRd[i]);
#pragma unroll
    for (int rb = 0; rb < 4; ++rb) {
      short8 a8 = __builtin_bit_cast(short8, af[rb]);
#pragma unroll
      for (int cb = 0; cb < 4; ++cb) {
        short8 b8 = __builtin_bit_cast(short8, bf[cb]);
        acc[rb][cb] = __builtin_amdgcn_mfma_f32_16x16x32_bf16(a8, b8, acc[rb][cb], 0, 0, 0);
      }
    }
    if ((s & 15) == 15) {   // end of pass j: fold with per-row weight, reset acc
      int j = s >> 4;
#pragma unroll
      for (int rb = 0; rb < 4; ++rb) {
        f32x4 wv = *(const f32x4*)&wLT[(j << 7) + wr * 64 + rb * 16 + ((lane >> 4) << 2)];
#pragma unroll
        for (int cb = 0; cb < 4; ++cb) {
          accO[rb][cb] += wv * acc[rb][cb];
          acc[rb][cb] = (f32x4){0,0,0,0};
        }
      }
    }
  }

  // epilogue: bias sum_j w_j[row]*b_ej[col], predicated scatter by token id
#pragma unroll
  for (int rb = 0; rb < 4; ++rb) {
    int rloc = wr * 64 + rb * 16 + ((lane >> 4) << 2);
    f32x4 wv[4];
#pragma unroll
    for (int j = 0; j < 4; ++j) wv[j] = *(const f32x4*)&wLT[(j << 7) + rloc];
    int tok[4]; bool pr[4];
#pragma unroll
    for (int q = 0; q < 4; ++q) {
      int rs = rloc + q; pr[q] = rs < cl;
      tok[q] = pr[q] ? (int)idx[base + rs] : 0;
    }
#pragma unroll
    for (int cb = 0; cb < 4; ++cb) {
      int cloc = wc * 64 + cb * 16 + (lane & 15);
      f32x4 v = accO[rb][cb];
#pragma unroll
      for (int j = 0; j < 4; ++j) v += wv[j] * bL[(j << 7) + cloc];
#pragma unroll
      for (int q = 0; q < 4; ++q)
        if (pr[q]) out[(size_t)tok[q] * DIM + tcol + cloc] = v[q];
    }
  }
}

extern "C" void kernel_launch(void* const* d_in, const int* in_sizes, int n_in,
                              void* d_out, int out_size, void* d_ws, size_t ws_size,
                              hipStream_t stream) {
  (void)in_sizes; (void)n_in; (void)out_size; (void)ws_size;
  const float* x   = (const float*)d_in[0];
  const float* srl = (const float*)d_in[1];
  const float* shl = (const float*)d_in[2];
  const float* sW  = (const float*)d_in[3];
  const float* sb  = (const float*)d_in[4];
  const float* hW  = (const float*)d_in[5];
  const float* hb  = (const float*)d_in[6];
  float* out = (float*)d_out;

  // workspace layout (~22.6 MB)
  char* ws = (char*)d_ws;
  float*    w4     = (float*)ws;     ws += TOK * 4 * 4;              // 256 KB
  int*      pairid = (int*)ws;       ws += TOK * 4;                  // 64 KB
  ushort_t* idx    = (ushort_t*)ws;  ws += (TOK + 128) * 2 + 256;    // ~33 KB
  int*      cntp   = (int*)ws;       ws += NPAIR * 4;
  int*      offp   = (int*)ws;       ws += NPAIR * 4;
  int*      curp   = (int*)ws;       ws += NPAIR * 4;
  int*      tsp    = (int*)ws;       ws += (NPAIR + 1) * 4;
  int*      tinfo  = (int*)ws;       ws += MAXTILES * 4 + 208;       // pad to 256B
  ushort_t* xg     = (ushort_t*)ws;  ws += (size_t)(TOK + 128) * DIM * 2;  // 16.9 MB
  ushort_t* wt     = (ushort_t*)ws;                                   // 5.25 MB

  hipMemsetAsync(cntp, 0, NPAIR * sizeof(int), stream);
  k_router<<<TOK / 256, 256, 0, stream>>>(srl, shl, w4, pairid, cntp);
  k_scan<<<1, 64, 0, stream>>>(cntp, offp, curp, tsp, tinfo, idx);
  k_fill<<<TOK / 256, 256, 0, stream>>>(pairid, curp, idx);
  k_gather<<<(TOK + 128) / 4, 256, 0, stream>>>(x, idx, xg);
  dim3 tb(32, 32, 1), tg(16, 16, 10);
  k_trw<<<tg, tb, 0, stream>>>(sW, hW, wt);
  k_moe<<<MAXTILES * 4, 256, 0, stream>>>(xg, wt, w4, idx, offp, cntp, tsp, tinfo,
                                          sb, hb, out);
}

// Round 4
// 119.073 us; speedup vs baseline: 1.5089x; 1.2761x over previous
//
#include <hip/hip_runtime.h>
#include <stdint.h>

typedef unsigned short ushort_t;
typedef __attribute__((ext_vector_type(8))) short short8;
typedef __attribute__((ext_vector_type(4))) float f32x4;
typedef __attribute__((ext_vector_type(4))) unsigned int u32x4;

#define TOK  16384
#define DIM  512
#define NPAIR 64          // pmin*8+pmax, only pmin<pmax used (28 live bins)
#define MAXTILES 156      // sum ceil(cnt/128) <= 128 + 28

// ---- helpers ----
__device__ __forceinline__ unsigned short f2bf(float f) {  // RNE f32->bf16
  union { float f; uint32_t u; } v; v.f = f;
  uint32_t u = v.u;
  uint32_t r = (u + 0x7fffu + ((u >> 16) & 1u)) >> 16;
  return (unsigned short)r;
}

// ---- kernel 1: router -> w4[t][4], pairid, per-pair counts (block-aggregated) ----
__global__ void k_router(const float* __restrict__ sl, const float* __restrict__ shl,
                         float* __restrict__ w4, int* __restrict__ pairid,
                         int* __restrict__ cnt) {
  __shared__ int h[NPAIR];
  int tid = threadIdx.x;
  int n = blockIdx.x * 256 + tid;
  if (tid < NPAIR) h[tid] = 0;
  __syncthreads();
  float l[8];
  float m = -1e30f;
#pragma unroll
  for (int i = 0; i < 8; ++i) { l[i] = sl[n*8 + i]; m = fmaxf(m, l[i]); }
  float s = 0.f;
#pragma unroll
  for (int i = 0; i < 8; ++i) { l[i] = expf(l[i] - m); s += l[i]; }
  float inv = 1.f / s;
#pragma unroll
  for (int i = 0; i < 8; ++i) l[i] *= inv;
  int i1 = 0; float v1 = l[0];
#pragma unroll
  for (int i = 1; i < 8; ++i) if (l[i] > v1) { v1 = l[i]; i1 = i; }
  int i2 = -1; float v2 = -1.f;
#pragma unroll
  for (int i = 0; i < 8; ++i) if (i != i1 && l[i] > v2) { v2 = l[i]; i2 = i; }
  float rs = 1.f / (v1 + v2 + 1e-6f);
  float w1 = v1 * rs, w2 = v2 * rs;
  int pmin, pmax; float wa, wb;
  if (i1 < i2) { pmin = i1; pmax = i2; wa = w1; wb = w2; }
  else         { pmin = i2; pmax = i1; wa = w2; wb = w1; }
  float s0 = shl[n*2], s1 = shl[n*2 + 1];
  float mm = fmaxf(s0, s1);
  float e0 = expf(s0 - mm), e1 = expf(s1 - mm);
  float si = 1.f / (e0 + e1);
  w4[n*4 + 0] = wa;
  w4[n*4 + 1] = wb;
  w4[n*4 + 2] = e0 * si;
  w4[n*4 + 3] = e1 * si;
  int p = pmin * 8 + pmax;
  pairid[n] = p;
  atomicAdd(&h[p], 1);                 // LDS atomic, low contention
  __syncthreads();
  if (tid < NPAIR && h[tid]) atomicAdd(&cnt[tid], h[tid]);  // <=64 per address
}

// ---- kernel 2: single-wave scan over 64 bins -> off/cursor/tileinfo ----
__global__ void k_scan(const int* __restrict__ cnt, int* __restrict__ off,
                       int* __restrict__ cursor, int* __restrict__ tsinfo,
                       int* __restrict__ tileinfo, ushort_t* __restrict__ idx) {
  int l = threadIdx.x;  // 64 threads = 1 wave
  int c = cnt[l];
  int t = (c + 127) >> 7;
  int sc = c, st = t;
#pragma unroll
  for (int d = 1; d < 64; d <<= 1) {
    int vc = __shfl_up(sc, d, 64);
    int vt = __shfl_up(st, d, 64);
    if (l >= d) { sc += vc; st += vt; }
  }
  int offv = sc - c, tsv = st - t;
  off[l] = offv; cursor[l] = offv;
  if (l == 63) tsinfo[64] = st;               // total row-tiles
  for (int q = 0; q < t; ++q) tileinfo[tsv + q] = (l << 16) | q;  // (pair, tstart)
  for (int i = l; i < 128; i += 64) idx[TOK + i] = 0;  // pad tail
}

// ---- kernel 3: fill packed token index (block-aggregated reservation) ----
__global__ void k_fill(const int* __restrict__ pairid, int* __restrict__ cursor,
                       ushort_t* __restrict__ idx) {
  __shared__ int hcnt[NPAIR];
  __shared__ int hbase[NPAIR];
  int tid = threadIdx.x;
  int n = blockIdx.x * 256 + tid;
  if (tid < NPAIR) hcnt[tid] = 0;
  __syncthreads();
  int p = pairid[n];
  int r = atomicAdd(&hcnt[p], 1);      // LDS atomic
  __syncthreads();
  if (tid < NPAIR && hcnt[tid]) hbase[tid] = atomicAdd(&cursor[tid], hcnt[tid]);
  __syncthreads();
  idx[hbase[p] + r] = (ushort_t)n;
}

// ---- kernel 4: fused gather + fp32->bf16 pack: xg[slot] = bf16(x[idx[slot]]) ----
__global__ void k_gather(const float* __restrict__ x, const ushort_t* __restrict__ idx,
                         ushort_t* __restrict__ xg) {
  int row = blockIdx.x * 4 + (threadIdx.x >> 6);
  int lane = threadIdx.x & 63;
  int t = (int)idx[row];
  const float* src = x + (size_t)t * DIM + lane * 8;
  f32x4 v0 = *(const f32x4*)src;
  f32x4 v1 = *(const f32x4*)(src + 4);
  u32x4 o;
  o[0] = (uint32_t)f2bf(v0[0]) | ((uint32_t)f2bf(v0[1]) << 16);
  o[1] = (uint32_t)f2bf(v0[2]) | ((uint32_t)f2bf(v0[3]) << 16);
  o[2] = (uint32_t)f2bf(v1[0]) | ((uint32_t)f2bf(v1[1]) << 16);
  o[3] = (uint32_t)f2bf(v1[2]) | ((uint32_t)f2bf(v1[3]) << 16);
  *(u32x4*)(xg + (size_t)row * DIM + lane * 8) = o;
}

// ---- kernel 5: W[e][d][f] fp32 -> Wt[e][f][d] bf16 ----
__global__ void k_trw(const float* __restrict__ wspec, const float* __restrict__ wsh,
                      ushort_t* __restrict__ wt) {
  __shared__ float t[32][33];
  int e = blockIdx.z;
  const float* src = (e < 8) ? (wspec + e * DIM * DIM) : (wsh + (e - 8) * DIM * DIM);
  int tx = threadIdx.x, ty = threadIdx.y;
  int d = blockIdx.y * 32 + ty, f = blockIdx.x * 32 + tx;
  t[ty][tx] = src[d * DIM + f];
  __syncthreads();
  int fo = blockIdx.x * 32 + ty, dd = blockIdx.y * 32 + tx;
  wt[(size_t)e * DIM * DIM + fo * DIM + dd] = f2bf(t[tx][ty]);
}

// ---- kernel 6: pair-grouped sparse MoE GEMM ----
// Block = 128 packed rows x 128 cols, 8 waves (wave tile 64x32), BK=64,
// double-buffered LDS, one __syncthreads per step (32 steps = 4 experts x 8 ks).
// Single accumulator via telescoping rescale: at pass boundary
// acc *= w_j[row]/w_{j+1}[row]; epilogue multiplies by w_3[row].
__global__ __launch_bounds__(512, 4)
void k_moe(const ushort_t* __restrict__ xg, const ushort_t* __restrict__ wt,
           const float* __restrict__ w4, const ushort_t* __restrict__ idx,
           const int* __restrict__ off, const int* __restrict__ cnt,
           const int* __restrict__ tsinfo, const int* __restrict__ tileinfo,
           const float* __restrict__ bspec, const float* __restrict__ bsh,
           float* __restrict__ out) {
  __shared__ char ldsA[2][16384];   // 128 rows x 128B (BK=64 bf16)
  __shared__ char ldsB[2][16384];
  __shared__ float wLT[4 * 128];    // per-pass per-row weight (pad rows = 1.0)
  __shared__ float bL[4 * 128];     // per-pass bias slice

  const int tid  = threadIdx.x;
  const int lane = tid & 63;
  const int w    = tid >> 6;        // 0..7
  const int wr   = w >> 2;          // 0..1 : row half (64 rows)
  const int wc   = w & 3;           // 0..3 : col quarter (32 cols)

  // XCD swizzle: 624 = 8 x 78; a row-tile's 4 col-blocks stay on one XCD (A reuse)
  int bx   = blockIdx.x;
  int slot = (bx & 7) * 78 + (bx >> 3);
  int r    = slot >> 2, cdx = slot & 3;
  if (r >= tsinfo[64]) return;
  int info = tileinfo[r];
  int p = info >> 16, tstart = info & 0xffff;
  const int base = off[p] + (tstart << 7);
  int cl = cnt[p] - (tstart << 7); if (cl > 128) cl = 128;
  const int e0 = p >> 3, e1 = p & 7;
  const int tcol = cdx << 7;

  // staging source offsets (elements): invert the 16B-slot XOR swizzle at source
  int soff[2];
#pragma unroll
  for (int q = 0; q < 2; ++q) {
    int pp  = (q << 13) + tid * 16;       // byte in 16KB buffer
    int row = pp >> 7;                    // 0..127
    int kb  = (pp & 127) ^ ((row & 7) << 4);
    soff[q] = row * DIM + (kb >> 1);
  }
  const ushort_t* aSrc = xg + (size_t)base * DIM;
  const ushort_t* bSrc = wt + (size_t)tcol * DIM;

  auto stage = [&](int s) {   // s = j*8 + ks; 4 vmem instr per thread
    int ks = s & 7, j = s >> 3, buf = s & 1;
    int e = (j == 0) ? e0 : (j == 1) ? e1 : (j == 2) ? 8 : 9;
    const ushort_t* a = aSrc + (ks << 6);
    const ushort_t* b = bSrc + ((size_t)e << 18) + (ks << 6);
#pragma unroll
    for (int q = 0; q < 2; ++q) {
      __builtin_amdgcn_global_load_lds(
          (const __attribute__((address_space(1))) void*)(a + soff[q]),
          (__attribute__((address_space(3))) void*)(&ldsA[buf][0] + (q << 13) + tid * 16),
          16, 0, 0);
      __builtin_amdgcn_global_load_lds(
          (const __attribute__((address_space(1))) void*)(b + soff[q]),
          (__attribute__((address_space(3))) void*)(&ldsB[buf][0] + (q << 13) + tid * 16),
          16, 0, 0);
    }
  };

  stage(0);

  // meta (512 threads -> one element each)
  {
    int j = tid >> 7, rs = tid & 127;
    wLT[tid] = (rs < cl) ? w4[(int)idx[base + rs] * 4 + j] : 1.0f;
  }
  {
    int j = tid >> 7, col = tid & 127;
    int e = (j == 0) ? e0 : (j == 1) ? e1 : (j == 2) ? 8 : 9;
    bL[tid] = (e < 8) ? bspec[e * DIM + tcol + col] : bsh[(e - 8) * DIM + tcol + col];
  }

  // swizzled LDS read offsets (bytes)
  int aRd[4][2], bRd[2][2];
#pragma unroll
  for (int rb = 0; rb < 4; ++rb) {
    int row = wr * 64 + rb * 16 + (lane & 15);
#pragma unroll
    for (int ksl = 0; ksl < 2; ++ksl) {
      int kb = ((ksl << 6) + ((lane >> 4) << 4)) ^ ((row & 7) << 4);
      aRd[rb][ksl] = row * 128 + kb;
    }
  }
#pragma unroll
  for (int cb = 0; cb < 2; ++cb) {
    int col = wc * 32 + cb * 16 + (lane & 15);
#pragma unroll
    for (int ksl = 0; ksl < 2; ++ksl) {
      int kb = ((ksl << 6) + ((lane >> 4) << 4)) ^ ((col & 7) << 4);
      bRd[cb][ksl] = col * 128 + kb;
    }
  }

  f32x4 acc[4][2];
#pragma unroll
  for (int a = 0; a < 4; ++a)
#pragma unroll
    for (int b = 0; b < 2; ++b) acc[a][b] = (f32x4){0.f, 0.f, 0.f, 0.f};

  __syncthreads();   // stage(0) landed; meta visible

#pragma unroll 1
  for (int s = 0; s < 32; ++s) {
    if (s < 31) stage(s + 1);          // into buf (s+1)&1, overlapped with compute
    const char* ab = &ldsA[s & 1][0];
    const char* bb = &ldsB[s & 1][0];
#pragma unroll
    for (int ksl = 0; ksl < 2; ++ksl) {
      u32x4 af[4], bf[2];
#pragma unroll
      for (int rb = 0; rb < 4; ++rb) af[rb] = *(const u32x4*)(ab + aRd[rb][ksl]);
#pragma unroll
      for (int cb = 0; cb < 2; ++cb) bf[cb] = *(const u32x4*)(bb + bRd[cb][ksl]);
#pragma unroll
      for (int rb = 0; rb < 4; ++rb) {
        short8 a8 = __builtin_bit_cast(short8, af[rb]);
#pragma unroll
        for (int cb = 0; cb < 2; ++cb) {
          short8 b8 = __builtin_bit_cast(short8, bf[cb]);
          acc[rb][cb] = __builtin_amdgcn_mfma_f32_16x16x32_bf16(a8, b8, acc[rb][cb], 0, 0, 0);
        }
      }
    }
    if ((s & 7) == 7 && s < 31) {      // pass boundary: acc *= w_j/w_{j+1}
      int j = s >> 3;
#pragma unroll
      for (int rb = 0; rb < 4; ++rb) {
        int rl = wr * 64 + rb * 16 + ((lane >> 4) << 2);
        f32x4 wp = *(const f32x4*)&wLT[(j << 7) + rl];
        f32x4 wn = *(const f32x4*)&wLT[((j + 1) << 7) + rl];
        f32x4 rv = wp / wn;
        acc[rb][0] *= rv;
        acc[rb][1] *= rv;
      }
    }
    __syncthreads();                   // drains stage(s+1); all waves done with buf
  }

  // epilogue: v = acc*w3 + sum_j w_j[row]*b_ej[col]; predicated scatter by token
#pragma unroll
  for (int rb = 0; rb < 4; ++rb) {
    int rl = wr * 64 + rb * 16 + ((lane >> 4) << 2);
    f32x4 wv[4];
#pragma unroll
    for (int j = 0; j < 4; ++j) wv[j] = *(const f32x4*)&wLT[(j << 7) + rl];
    int tok[4]; bool pr[4];
#pragma unroll
    for (int q = 0; q < 4; ++q) {
      int rs = rl + q; pr[q] = rs < cl;
      tok[q] = pr[q] ? (int)idx[base + rs] : 0;
    }
#pragma unroll
    for (int cb = 0; cb < 2; ++cb) {
      int cloc = wc * 32 + cb * 16 + (lane & 15);
      f32x4 v = acc[rb][cb] * wv[3];
#pragma unroll
      for (int j = 0; j < 4; ++j) v += wv[j] * bL[(j << 7) + cloc];
#pragma unroll
      for (int q = 0; q < 4; ++q)
        if (pr[q]) out[(size_t)tok[q] * DIM + tcol + cloc] = v[q];
    }
  }
}

extern "C" void kernel_launch(void* const* d_in, const int* in_sizes, int n_in,
                              void* d_out, int out_size, void* d_ws, size_t ws_size,
                              hipStream_t stream) {
  (void)in_sizes; (void)n_in; (void)out_size; (void)ws_size;
  const float* x   = (const float*)d_in[0];
  const float* srl = (const float*)d_in[1];
  const float* shl = (const float*)d_in[2];
  const float* sW  = (const float*)d_in[3];
  const float* sb  = (const float*)d_in[4];
  const float* hW  = (const float*)d_in[5];
  const float* hb  = (const float*)d_in[6];
  float* out = (float*)d_out;

  // workspace layout (~22.6 MB)
  char* ws = (char*)d_ws;
  float*    w4     = (float*)ws;     ws += TOK * 4 * 4;              // 256 KB
  int*      pairid = (int*)ws;       ws += TOK * 4;                  // 64 KB
  ushort_t* idx    = (ushort_t*)ws;  ws += (TOK + 128) * 2 + 256;    // ~33 KB
  int*      cntp   = (int*)ws;       ws += NPAIR * 4;
  int*      offp   = (int*)ws;       ws += NPAIR * 4;
  int*      curp   = (int*)ws;       ws += NPAIR * 4;
  int*      tsp    = (int*)ws;       ws += (NPAIR + 1) * 4;
  int*      tinfo  = (int*)ws;       ws += MAXTILES * 4 + 208;       // pad to 256B
  ushort_t* xg     = (ushort_t*)ws;  ws += (size_t)(TOK + 128) * DIM * 2;  // 16.9 MB
  ushort_t* wt     = (ushort_t*)ws;                                   // 5.25 MB

  hipMemsetAsync(cntp, 0, NPAIR * sizeof(int), stream);
  k_router<<<TOK / 256, 256, 0, stream>>>(srl, shl, w4, pairid, cntp);
  k_scan<<<1, 64, 0, stream>>>(cntp, offp, curp, tsp, tinfo, idx);
  k_fill<<<TOK / 256, 256, 0, stream>>>(pairid, curp, idx);
  k_gather<<<(TOK + 128) / 4, 256, 0, stream>>>(x, idx, xg);
  dim3 tb(32, 32, 1), tg(16, 16, 10);
  k_trw<<<tg, tb, 0, stream>>>(sW, hW, wt);
  k_moe<<<MAXTILES * 4, 512, 0, stream>>>(xg, wt, w4, idx, offp, cntp, tsp, tinfo,
                                          sb, hb, out);
}

// Round 5
// 91.167 us; speedup vs baseline: 1.9707x; 1.3061x over previous
//
#include <hip/hip_runtime.h>
#include <stdint.h>

typedef unsigned short ushort_t;
typedef __attribute__((ext_vector_type(8))) short short8;
typedef __attribute__((ext_vector_type(4))) float f32x4;
typedef __attribute__((ext_vector_type(4))) unsigned int u32x4;

#define TOK  16384
#define DIM  512
#define NPAIR 64          // pmin*8+pmax, only pmin<pmax used (28 live bins)
#define MAXTILES 156      // sum ceil(cnt/128) <= 128 + 28

// ---- helpers ----
__device__ __forceinline__ unsigned short f2bf(float f) {  // RNE f32->bf16
  union { float f; uint32_t u; } v; v.f = f;
  uint32_t u = v.u;
  uint32_t r = (u + 0x7fffu + ((u >> 16) & 1u)) >> 16;
  return (unsigned short)r;
}

// ---- kernel 1: router -> w4[t][4], pairid, per-pair counts (block-aggregated) ----
__global__ void k_router(const float* __restrict__ sl, const float* __restrict__ shl,
                         float* __restrict__ w4, int* __restrict__ pairid,
                         int* __restrict__ cnt) {
  __shared__ int h[NPAIR];
  int tid = threadIdx.x;
  int n = blockIdx.x * 256 + tid;
  if (tid < NPAIR) h[tid] = 0;
  __syncthreads();
  float l[8];
  float m = -1e30f;
#pragma unroll
  for (int i = 0; i < 8; ++i) { l[i] = sl[n*8 + i]; m = fmaxf(m, l[i]); }
  float s = 0.f;
#pragma unroll
  for (int i = 0; i < 8; ++i) { l[i] = expf(l[i] - m); s += l[i]; }
  float inv = 1.f / s;
#pragma unroll
  for (int i = 0; i < 8; ++i) l[i] *= inv;
  int i1 = 0; float v1 = l[0];
#pragma unroll
  for (int i = 1; i < 8; ++i) if (l[i] > v1) { v1 = l[i]; i1 = i; }
  int i2 = -1; float v2 = -1.f;
#pragma unroll
  for (int i = 0; i < 8; ++i) if (i != i1 && l[i] > v2) { v2 = l[i]; i2 = i; }
  float rs = 1.f / (v1 + v2 + 1e-6f);
  float w1 = v1 * rs, w2 = v2 * rs;
  int pmin, pmax; float wa, wb;
  if (i1 < i2) { pmin = i1; pmax = i2; wa = w1; wb = w2; }
  else         { pmin = i2; pmax = i1; wa = w2; wb = w1; }
  float s0 = shl[n*2], s1 = shl[n*2 + 1];
  float mm = fmaxf(s0, s1);
  float e0 = expf(s0 - mm), e1 = expf(s1 - mm);
  float si = 1.f / (e0 + e1);
  w4[n*4 + 0] = wa;
  w4[n*4 + 1] = wb;
  w4[n*4 + 2] = e0 * si;
  w4[n*4 + 3] = e1 * si;
  int p = pmin * 8 + pmax;
  pairid[n] = p;
  atomicAdd(&h[p], 1);                 // LDS atomic, low contention
  __syncthreads();
  if (tid < NPAIR && h[tid]) atomicAdd(&cnt[tid], h[tid]);  // <=64 per address
}

// ---- kernel 2: single-wave scan over 64 bins -> off/cursor/tileinfo ----
__global__ void k_scan(const int* __restrict__ cnt, int* __restrict__ off,
                       int* __restrict__ cursor, int* __restrict__ tsinfo,
                       int* __restrict__ tileinfo, ushort_t* __restrict__ idx) {
  int l = threadIdx.x;  // 64 threads = 1 wave
  int c = cnt[l];
  int t = (c + 127) >> 7;
  int sc = c, st = t;
#pragma unroll
  for (int d = 1; d < 64; d <<= 1) {
    int vc = __shfl_up(sc, d, 64);
    int vt = __shfl_up(st, d, 64);
    if (l >= d) { sc += vc; st += vt; }
  }
  int offv = sc - c, tsv = st - t;
  off[l] = offv; cursor[l] = offv;
  if (l == 63) tsinfo[64] = st;               // total row-tiles
  for (int q = 0; q < t; ++q) tileinfo[tsv + q] = (l << 16) | q;  // (pair, tstart)
  for (int i = l; i < 128; i += 64) idx[TOK + i] = 0;  // pad tail
}

// ---- kernel 3: fill packed token index (block-aggregated reservation) ----
__global__ void k_fill(const int* __restrict__ pairid, int* __restrict__ cursor,
                       ushort_t* __restrict__ idx) {
  __shared__ int hcnt[NPAIR];
  __shared__ int hbase[NPAIR];
  int tid = threadIdx.x;
  int n = blockIdx.x * 256 + tid;
  if (tid < NPAIR) hcnt[tid] = 0;
  __syncthreads();
  int p = pairid[n];
  int r = atomicAdd(&hcnt[p], 1);      // LDS atomic
  __syncthreads();
  if (tid < NPAIR && hcnt[tid]) hbase[tid] = atomicAdd(&cursor[tid], hcnt[tid]);
  __syncthreads();
  idx[hbase[p] + r] = (ushort_t)n;
}

// ---- kernel 4: fused gather + fp32->bf16 pack: xg[slot] = bf16(x[idx[slot]]) ----
__global__ void k_gather(const float* __restrict__ x, const ushort_t* __restrict__ idx,
                         ushort_t* __restrict__ xg) {
  int row = blockIdx.x * 4 + (threadIdx.x >> 6);
  int lane = threadIdx.x & 63;
  int t = (int)idx[row];
  const float* src = x + (size_t)t * DIM + lane * 8;
  f32x4 v0 = *(const f32x4*)src;
  f32x4 v1 = *(const f32x4*)(src + 4);
  u32x4 o;
  o[0] = (uint32_t)f2bf(v0[0]) | ((uint32_t)f2bf(v0[1]) << 16);
  o[1] = (uint32_t)f2bf(v0[2]) | ((uint32_t)f2bf(v0[3]) << 16);
  o[2] = (uint32_t)f2bf(v1[0]) | ((uint32_t)f2bf(v1[1]) << 16);
  o[3] = (uint32_t)f2bf(v1[2]) | ((uint32_t)f2bf(v1[3]) << 16);
  *(u32x4*)(xg + (size_t)row * DIM + lane * 8) = o;
}

// ---- kernel 5: W[e][d][f] fp32 -> Wt[e][f][d] bf16 ----
__global__ void k_trw(const float* __restrict__ wspec, const float* __restrict__ wsh,
                      ushort_t* __restrict__ wt) {
  __shared__ float t[32][33];
  int e = blockIdx.z;
  const float* src = (e < 8) ? (wspec + e * DIM * DIM) : (wsh + (e - 8) * DIM * DIM);
  int tx = threadIdx.x, ty = threadIdx.y;
  int d = blockIdx.y * 32 + ty, f = blockIdx.x * 32 + tx;
  t[ty][tx] = src[d * DIM + f];
  __syncthreads();
  int fo = blockIdx.x * 32 + ty, dd = blockIdx.y * 32 + tx;
  wt[(size_t)e * DIM * DIM + fo * DIM + dd] = f2bf(t[tx][ty]);
}

// ---- kernel 6: pair-grouped sparse MoE GEMM (m97-cadence, expert-minor) ----
// Block = 128 packed rows x 128 cols, 4 waves (wave tile 64x64), BK=64.
// Loop s = ks*4 + j (32 steps): A staged once per ks and reused across the
// 4 experts {e0,e1,8,9}; B staged every step. Single-buffered LDS, two
// barriers per step (m97 cadence); 3 blocks/CU stagger hides the drain.
// ONE accumulator via cyclic telescoping: after phase j, acc *= w_j/w_{(j+1)&3}
// (full cycle product = 1 => term from phase j ends scaled w_j/w_3; epilogue x w_3).
__global__ __launch_bounds__(256, 3)
void k_moe(const ushort_t* __restrict__ xg, const ushort_t* __restrict__ wt,
           const float* __restrict__ w4, const ushort_t* __restrict__ idx,
           const int* __restrict__ off, const int* __restrict__ cnt,
           const int* __restrict__ tsinfo, const int* __restrict__ tileinfo,
           const float* __restrict__ bspec, const float* __restrict__ bsh,
           float* __restrict__ out) {
  __shared__ ushort_t aB[8192];     // 16KB: 128 rows x 64k bf16, XOR-swizzled
  __shared__ ushort_t bB[8192];     // 16KB
  __shared__ float wLT[4 * 128];    // w_j[row] (pad rows = 1.0)
  __shared__ float wRT[4 * 128];    // w_j[row]/w_{(j+1)&3}[row]
  __shared__ float bL[4 * 128];     // bias slice per phase

  const int tid  = threadIdx.x;
  const int lane = tid & 63;
  const int w    = tid >> 6;        // 0..3
  const int wr   = w >> 1, wc = w & 1;

  // XCD swizzle: 624 = 8 x 78; a row-tile's 4 col-blocks stay on one XCD
  int bx   = blockIdx.x;
  int slot = (bx & 7) * 78 + (bx >> 3);
  int r    = slot >> 2, cdx = slot & 3;
  if (r >= tsinfo[64]) return;
  int info = tileinfo[r];
  int p = info >> 16, tstart = info & 0xffff;
  const int base = off[p] + (tstart << 7);
  int cl = cnt[p] - (tstart << 7); if (cl > 128) cl = 128;
  const int e0 = p >> 3, e1 = p & 7;
  const int tcol = cdx << 7;

  // staging source offsets: invert the 16B-slot XOR swizzle at the source
  int soff[4];
#pragma unroll
  for (int q = 0; q < 4; ++q) {
    int pp  = (q << 12) + tid * 16;       // byte in 16KB buffer
    int row = pp >> 7;                    // 0..127
    int kb  = (pp & 127) ^ ((row & 7) << 4);
    soff[q] = row * DIM + (kb >> 1);
  }
  const ushort_t* aSrc = xg + (size_t)base * DIM;
  const ushort_t* bSrc = wt + (size_t)tcol * DIM;

  // meta: weights, telescoping ratios, bias
  for (int i = tid; i < 512; i += 256) {
    int j = i >> 7, rs = i & 127;
    float wa = 1.f, wb = 1.f;
    if (rs < cl) {
      int t = (int)idx[base + rs];
      wa = w4[t * 4 + j];
      wb = w4[t * 4 + ((j + 1) & 3)];
    }
    wLT[i] = wa;
    wRT[i] = wa / wb;
  }
  for (int i = tid; i < 512; i += 256) {
    int j = i >> 7, col = i & 127;
    int e = (j == 0) ? e0 : (j == 1) ? e1 : (j == 2) ? 8 : 9;
    bL[i] = (e < 8) ? bspec[e * DIM + tcol + col] : bsh[(e - 8) * DIM + tcol + col];
  }

  // swizzled LDS read offsets (bytes)
  int aRd[4][2], bRd[4][2];
#pragma unroll
  for (int i = 0; i < 4; ++i) {
    int row = wr * 64 + i * 16 + (lane & 15);
#pragma unroll
    for (int ksl = 0; ksl < 2; ++ksl) {
      int kb = ((ksl << 6) + ((lane >> 4) << 4)) ^ ((row & 7) << 4);
      aRd[i][ksl] = row * 128 + kb;
    }
    int col = wc * 64 + i * 16 + (lane & 15);
#pragma unroll
    for (int ksl = 0; ksl < 2; ++ksl) {
      int kb = ((ksl << 6) + ((lane >> 4) << 4)) ^ ((col & 7) << 4);
      bRd[i][ksl] = col * 128 + kb;
    }
  }

  f32x4 acc[4][4];
#pragma unroll
  for (int a = 0; a < 4; ++a)
#pragma unroll
    for (int b = 0; b < 4; ++b) acc[a][b] = (f32x4){0.f, 0.f, 0.f, 0.f};

#pragma unroll 1
  for (int s = 0; s < 32; ++s) {
    int ks = s >> 2, j = s & 3;
    if (j == 0) {                      // A staged once per ks, reused 4x
#pragma unroll
      for (int q = 0; q < 4; ++q)
        __builtin_amdgcn_global_load_lds(
            (const __attribute__((address_space(1))) void*)(aSrc + (ks << 6) + soff[q]),
            (__attribute__((address_space(3))) void*)((char*)aB + (q << 12) + tid * 16),
            16, 0, 0);
    }
    {
      int e = (j == 0) ? e0 : (j == 1) ? e1 : (j == 2) ? 8 : 9;
      const ushort_t* b = bSrc + ((size_t)e << 18) + (ks << 6);
#pragma unroll
      for (int q = 0; q < 4; ++q)
        __builtin_amdgcn_global_load_lds(
            (const __attribute__((address_space(1))) void*)(b + soff[q]),
            (__attribute__((address_space(3))) void*)((char*)bB + (q << 12) + tid * 16),
            16, 0, 0);
    }
    __syncthreads();                   // drain stage(s) (+ meta on s=0)

    u32x4 af[4][2], bf[4][2];
#pragma unroll
    for (int i = 0; i < 4; ++i)
#pragma unroll
      for (int ksl = 0; ksl < 2; ++ksl) {
        af[i][ksl] = *(const u32x4*)((const char*)aB + aRd[i][ksl]);
        bf[i][ksl] = *(const u32x4*)((const char*)bB + bRd[i][ksl]);
      }
#pragma unroll
    for (int ksl = 0; ksl < 2; ++ksl)
#pragma unroll
      for (int rb = 0; rb < 4; ++rb) {
        short8 a8 = __builtin_bit_cast(short8, af[rb][ksl]);
#pragma unroll
        for (int cb = 0; cb < 4; ++cb) {
          short8 b8 = __builtin_bit_cast(short8, bf[cb][ksl]);
          acc[rb][cb] = __builtin_amdgcn_mfma_f32_16x16x32_bf16(a8, b8, acc[rb][cb], 0, 0, 0);
        }
      }

    if (s < 31) {                      // telescope boundary: acc *= w_j/w_{j+1}
#pragma unroll
      for (int rb = 0; rb < 4; ++rb) {
        int rl = wr * 64 + rb * 16 + ((lane >> 4) << 2);
        f32x4 rv = *(const f32x4*)&wRT[(j << 7) + rl];
#pragma unroll
        for (int cb = 0; cb < 4; ++cb) acc[rb][cb] *= rv;
      }
    }
    __syncthreads();                   // WAR: nobody overwrites LDS early
  }

  // epilogue: v = acc*w3 + sum_j w_j[row]*b_ej[col]; predicated scatter by token
#pragma unroll
  for (int rb = 0; rb < 4; ++rb) {
    int rl = wr * 64 + rb * 16 + ((lane >> 4) << 2);
    f32x4 wv[4];
#pragma unroll
    for (int j = 0; j < 4; ++j) wv[j] = *(const f32x4*)&wLT[(j << 7) + rl];
    int tok[4]; bool pr[4];
#pragma unroll
    for (int q = 0; q < 4; ++q) {
      int rs = rl + q; pr[q] = rs < cl;
      tok[q] = pr[q] ? (int)idx[base + rs] : 0;
    }
#pragma unroll
    for (int cb = 0; cb < 4; ++cb) {
      int cloc = wc * 64 + cb * 16 + (lane & 15);
      f32x4 v = acc[rb][cb] * wv[3];
#pragma unroll
      for (int j = 0; j < 4; ++j) v += wv[j] * bL[(j << 7) + cloc];
#pragma unroll
      for (int q = 0; q < 4; ++q)
        if (pr[q]) out[(size_t)tok[q] * DIM + tcol + cloc] = v[q];
    }
  }
}

extern "C" void kernel_launch(void* const* d_in, const int* in_sizes, int n_in,
                              void* d_out, int out_size, void* d_ws, size_t ws_size,
                              hipStream_t stream) {
  (void)in_sizes; (void)n_in; (void)out_size; (void)ws_size;
  const float* x   = (const float*)d_in[0];
  const float* srl = (const float*)d_in[1];
  const float* shl = (const float*)d_in[2];
  const float* sW  = (const float*)d_in[3];
  const float* sb  = (const float*)d_in[4];
  const float* hW  = (const float*)d_in[5];
  const float* hb  = (const float*)d_in[6];
  float* out = (float*)d_out;

  // workspace layout (~22.6 MB)
  char* ws = (char*)d_ws;
  float*    w4     = (float*)ws;     ws += TOK * 4 * 4;              // 256 KB
  int*      pairid = (int*)ws;       ws += TOK * 4;                  // 64 KB
  ushort_t* idx    = (ushort_t*)ws;  ws += (TOK + 128) * 2 + 256;    // ~33 KB
  int*      cntp   = (int*)ws;       ws += NPAIR * 4;
  int*      offp   = (int*)ws;       ws += NPAIR * 4;
  int*      curp   = (int*)ws;       ws += NPAIR * 4;
  int*      tsp    = (int*)ws;       ws += (NPAIR + 1) * 4;
  int*      tinfo  = (int*)ws;       ws += MAXTILES * 4 + 208;       // pad to 256B
  ushort_t* xg     = (ushort_t*)ws;  ws += (size_t)(TOK + 128) * DIM * 2;  // 16.9 MB
  ushort_t* wt     = (ushort_t*)ws;                                   // 5.25 MB

  hipMemsetAsync(cntp, 0, NPAIR * sizeof(int), stream);
  k_router<<<TOK / 256, 256, 0, stream>>>(srl, shl, w4, pairid, cntp);
  k_scan<<<1, 64, 0, stream>>>(cntp, offp, curp, tsp, tinfo, idx);
  k_fill<<<TOK / 256, 256, 0, stream>>>(pairid, curp, idx);
  k_gather<<<(TOK + 128) / 4, 256, 0, stream>>>(x, idx, xg);
  dim3 tb(32, 32, 1), tg(16, 16, 10);
  k_trw<<<tg, tb, 0, stream>>>(sW, hW, wt);
  k_moe<<<MAXTILES * 4, 256, 0, stream>>>(xg, wt, w4, idx, offp, cntp, tsp, tinfo,
                                          sb, hb, out);
}